// Round 12
// baseline (964.681 us; speedup 1.0000x reference)
//
#include <hip/hip_runtime.h>
#include <stdint.h>

#define N_IMGS 8
#define C 256
#define H 128
#define W 128
#define R 1024
#define HOUT 14
#define WOUT 14
#define NPOS 196          // HOUT*WOUT
#define HW (H * W)        // 16384
#define IMG_ELEMS (C * HW)
#define CTILE 32          // channels per roi item
#define NCT (C / CTILE)   // 8 channel tiles per roi
#define TILE_ELEMS (CTILE * NPOS)  // 6272 floats, contiguous in output
#define CU_ (C / 2)       // uints per NHWC row (bf16-pair packed) = 128

// Persistent-kernel work queue geometry.
#define TRT_PER_IMG 1024                 // 4 cgroups(64ch) x 256 hwtiles(64hw)
#define TR_ITEMS (N_IMGS * TRT_PER_IMG)  // 8192
#define ROI_ITEMS (R * NCT)              // 8192
#define TOTAL_ITEMS (1 + TR_ITEMS + ROI_ITEMS)
#define GRID_PERSIST 768                 // 3 blocks/CU x 256 CUs, co-resident

typedef float f4_t __attribute__((ext_vector_type(4)));
typedef float f2_t __attribute__((ext_vector_type(2)));

__device__ __forceinline__ unsigned short f2bf(float f) {  // RTNE
  uint32_t u = __float_as_uint(f);
  uint32_t r = u + 0x7FFFu + ((u >> 16) & 1u);
  return (unsigned short)(r >> 16);
}

// Unpack one bf16 pair (packed uint) to {lo, hi} floats.
__device__ __forceinline__ f2_t up2(uint32_t q) {
  f2_t v;
  v.x = __uint_as_float(q << 16);
  v.y = __uint_as_float(q & 0xFFFF0000u);
  return v;
}

// Bilinear combine for 8 channels (4 bf16 pairs) of one position; float2
// vector math -> packed f32 FMA where available.
__device__ __forceinline__ void acc8(float* s_base, int p, uint4 a, uint4 b,
                                     uint4 c, uint4 d, float4 w) {
  const uint32_t qa[4] = {a.x, a.y, a.z, a.w};
  const uint32_t qb[4] = {b.x, b.y, b.z, b.w};
  const uint32_t qc[4] = {c.x, c.y, c.z, c.w};
  const uint32_t qd[4] = {d.x, d.y, d.z, d.w};
#pragma unroll
  for (int j = 0; j < 4; ++j) {
    f2_t acc = up2(qa[j]) * w.x;
    acc += up2(qb[j]) * w.y;
    acc += up2(qc[j]) * w.z;
    acc += up2(qd[j]) * w.w;
    s_base[(2 * j + 0) * NPOS + p] = acc.x;
    s_base[(2 * j + 1) * NPOS + p] = acc.y;
  }
}

// ---------------------------------------------------------------------------
// Geometry precompute: offsets (pre-scaled by SCALE) and bilinear weights
// for all 196 positions of roi r into LDS.
// ---------------------------------------------------------------------------
template <int SCALE>
__device__ __forceinline__ void setup_roi(const float* __restrict__ rois,
                                          int r, int tid, int4* s_off,
                                          float4* s_w, int* s_n) {
  const float bf = rois[r * 5 + 0];
  const float x1 = rois[r * 5 + 1];
  const float y1 = rois[r * 5 + 2];
  const float x2 = rois[r * 5 + 3];
  const float y2 = rois[r * 5 + 4];
  if (tid == 0) *s_n = (int)bf;

  if (tid < NPOS) {
    const int ph = tid / WOUT;
    const int pw = tid - ph * WOUT;
    const float px_rel = (pw + 0.5f) / (float)WOUT;
    const float py_rel = (ph + 0.5f) / (float)HOUT;
    const float x_abs = px_rel * (x2 - x1) + x1;
    const float y_abs = py_rel * (y2 - y1) + y1;
    // rx = x_abs / W * 0.25 ; px = rx * W - 0.5  ==  x_abs * 0.25 - 0.5
    const float px = x_abs * 0.25f - 0.5f;
    const float py = y_abs * 0.25f - 0.5f;
    const float x0f = floorf(px);
    const float y0f = floorf(py);
    const float lx = px - x0f, ly = py - y0f;
    const float hx = 1.0f - lx, hy = 1.0f - ly;
    const int ix0 = (int)x0f;
    const int iy0 = (int)y0f;
    const int ix1 = ix0 + 1;
    const int iy1 = iy0 + 1;
    // Reference pads with zeros and clips into the pad -> OOB corners
    // contribute exactly 0. Reproduce by zeroing the weight.
    const bool vx0 = (ix0 >= 0) && (ix0 < W);
    const bool vx1 = (ix1 >= 0) && (ix1 < W);
    const bool vy0 = (iy0 >= 0) && (iy0 < H);
    const bool vy1 = (iy1 >= 0) && (iy1 < H);
    const int cx0 = min(max(ix0, 0), W - 1);
    const int cx1 = min(max(ix1, 0), W - 1);
    const int cy0 = min(max(iy0, 0), H - 1);
    const int cy1 = min(max(iy1, 0), H - 1);
    int4 o;
    o.x = (cy0 * W + cx0) * SCALE;
    o.y = (cy1 * W + cx0) * SCALE;
    o.z = (cy0 * W + cx1) * SCALE;
    o.w = (cy1 * W + cx1) * SCALE;
    float4 w4;
    w4.x = (vx0 && vy0) ? hx * hy : 0.0f;
    w4.y = (vx0 && vy1) ? hx * ly : 0.0f;
    w4.z = (vx1 && vy0) ? lx * hy : 0.0f;
    w4.w = (vx1 && vy1) ? lx * ly : 0.0f;
    s_off[tid] = o;
    s_w[tid]   = w4;
  }
}

// ---------------------------------------------------------------------------
// Fused persistent kernel. Work queue (global ticket in flg[0]):
//   item 0                  : counting-sort rois by image -> perm (NT stores)
//   items 1..8192           : transpose tiles (64ch x 64hw), image-major,
//                             bf16-packed NHWC written with NT (write-through)
//                             stores so consumers on other XCDs read via LLC.
//   items 8193..16384       : roi tiles (image-grouped via perm). tid0 spins
//                             (relaxed agent loads, no L2-invalidating
//                             acquire -> gather set stays L2-resident) on
//                             sort_done (flg[1]) and img_done (flg[2+n]).
// Queue order guarantees all transpose items are claimed before any roi item
// -> spinners always have live producers -> no deadlock (co-residency not
// required; grid 768 is co-resident anyway at 3 blocks/CU).
// flg[0..9] zeroed by hipMemsetAsync each launch.
// ---------------------------------------------------------------------------
__global__ __launch_bounds__(512, 6) void fused_roialign(
    const float* __restrict__ feats, const float* __restrict__ rois,
    uint32_t* __restrict__ nhwc, int* __restrict__ perm,
    int* __restrict__ flg, float* __restrict__ out) {
  __shared__ alignas(16) char smem[31360];  // max(roi 31360, tile 16640, sort)
  __shared__ int s_ticket, s_r, s_n;
  const int tid = threadIdx.x;

  for (;;) {
    if (tid == 0)
      s_ticket = __hip_atomic_fetch_add(&flg[0], 1, __ATOMIC_RELAXED,
                                        __HIP_MEMORY_SCOPE_AGENT);
    __syncthreads();
    const int it = s_ticket;
    if (it >= TOTAL_ITEMS) return;

    if (it == 0) {
      // ---------------- sort rois by image ----------------
      int* hist = (int*)smem;
      int* cursor = hist + N_IMGS;
      if (tid < N_IMGS) hist[tid] = 0;
      __syncthreads();
      for (int i = tid; i < R; i += 512)
        atomicAdd(&hist[(int)rois[i * 5]], 1);
      __syncthreads();
      if (tid == 0) {
        int acc = 0;
        for (int k = 0; k < N_IMGS; ++k) {
          cursor[k] = acc;
          acc += hist[k];
        }
      }
      __syncthreads();
      for (int i = tid; i < R; i += 512) {
        const int b = (int)rois[i * 5];
        const int pos = atomicAdd(&cursor[b], 1);
        __builtin_nontemporal_store(i, &perm[pos]);  // write-through to LLC
      }
      __syncthreads();  // drains stores before publish
      if (tid == 0)
        __hip_atomic_fetch_add(&flg[1], 1, __ATOMIC_RELEASE,
                               __HIP_MEMORY_SCOPE_AGENT);
    } else if (it <= TR_ITEMS) {
      // ---------------- transpose tile: 64 ch x 64 hw ----------------
      const int t = it - 1;
      const int n = t >> 10;
      const int rem = t & 1023;
      const int c0 = (rem >> 8) * 64;
      const int hw0 = (rem & 255) * 64;
      float(*tile)[65] = (float(*)[65])smem;
      const float* inp = feats + (size_t)n * IMG_ELEMS;
      uint32_t* outp = nhwc + (size_t)n * (size_t)HW * CU_;
      const int tx = tid & 63, trow = tid >> 6;  // 8 loader rows
#pragma unroll
      for (int i = 0; i < 8; ++i) {
        const int cc = trow + i * 8;
        tile[cc][tx] = inp[(size_t)(c0 + cc) * HW + hw0 + tx];
      }
      __syncthreads();
      const int u = tid & 31, hrow = tid >> 5;  // 16 storer rows
#pragma unroll
      for (int i = 0; i < 4; ++i) {
        const int hh = hrow + i * 16;
        const uint32_t lo = f2bf(tile[2 * u + 0][hh]);
        const uint32_t hi = f2bf(tile[2 * u + 1][hh]);
        __builtin_nontemporal_store(
            lo | (hi << 16),
            &outp[(size_t)(hw0 + hh) * CU_ + (c0 >> 1) + u]);
      }
      __syncthreads();  // all NT stores drained (barrier waits vmcnt)
      if (tid == 0)
        __hip_atomic_fetch_add(&flg[2 + n], 1, __ATOMIC_RELEASE,
                               __HIP_MEMORY_SCOPE_AGENT);
    } else {
      // ---------------- roi item ----------------
      const int q = it - 1 - TR_ITEMS;
      const int sp = q >> 3;
      const int ct = q & 7;
      if (tid == 0) {
        while (__hip_atomic_load(&flg[1], __ATOMIC_RELAXED,
                                 __HIP_MEMORY_SCOPE_AGENT) == 0)
          __builtin_amdgcn_s_sleep(2);
        asm volatile("" ::: "memory");  // compiler fence: perm load after flag
        const int r = perm[sp];
        s_r = r;
        const int n = (int)rois[r * 5];
        while (__hip_atomic_load(&flg[2 + n], __ATOMIC_RELAXED,
                                 __HIP_MEMORY_SCOPE_AGENT) < TRT_PER_IMG)
          __builtin_amdgcn_s_sleep(8);
        asm volatile("" ::: "memory");
      }
      __syncthreads();
      const int r = s_r;
      const int c0 = ct * CTILE;

      int4* s_off = (int4*)smem;
      float4* s_w = (float4*)(smem + 3136);
      float* s_res = (float*)(smem + 6272);

      setup_roi<CU_>(rois, r, tid, s_off, s_w, &s_n);
      __syncthreads();

      const int lc8 = tid & 3;   // channel octet within tile
      const int g = tid >> 2;    // 0..127 position group
      const uint32_t* base =
          nhwc + (size_t)s_n * (size_t)HW * CU_ + (c0 >> 1) + lc8 * 4;
      float* s_base = s_res + (lc8 * 8) * NPOS;

      const bool has1 = g < (NPOS - 128);  // g < 68
      const int p1 = 128 + g;

      const int4 o0 = s_off[g];
      const float4 w0 = s_w[g];
      uint4 A0 = *reinterpret_cast<const uint4*>(base + o0.x);
      uint4 B0 = *reinterpret_cast<const uint4*>(base + o0.y);
      uint4 C0 = *reinterpret_cast<const uint4*>(base + o0.z);
      uint4 D0 = *reinterpret_cast<const uint4*>(base + o0.w);
      if (has1) {
        const int4 o1 = s_off[p1];
        const float4 w1 = s_w[p1];
        const uint4 A1 = *reinterpret_cast<const uint4*>(base + o1.x);
        const uint4 B1 = *reinterpret_cast<const uint4*>(base + o1.y);
        const uint4 C1 = *reinterpret_cast<const uint4*>(base + o1.z);
        const uint4 D1 = *reinterpret_cast<const uint4*>(base + o1.w);
        acc8(s_base, g, A0, B0, C0, D0, w0);
        acc8(s_base, p1, A1, B1, C1, D1, w1);
      } else {
        acc8(s_base, g, A0, B0, C0, D0, w0);
      }
      __syncthreads();

      // Stream the tile out: contiguous 25088B, nontemporal 16B stores.
      const f4_t* s4 = reinterpret_cast<const f4_t*>(s_res);
      f4_t* out4 =
          reinterpret_cast<f4_t*>(out + ((size_t)r * C + c0) * NPOS);
#pragma unroll 1
      for (int i = tid; i < TILE_ELEMS / 4; i += 512) {
        __builtin_nontemporal_store(s4[i], &out4[i]);
      }
    }
    __syncthreads();  // protect LDS reuse before next ticket claim
  }
}

// ---------------------------------------------------------------------------
// Fallback (ws too small): scalar gathers straight from NCHW. Correct, slow.
// ---------------------------------------------------------------------------
__global__ __launch_bounds__(256, 4) void roi_align_nchw(
    const float* __restrict__ feats, const float* __restrict__ rois,
    float* __restrict__ out) {
  __shared__ int4 s_off[NPOS];
  __shared__ float4 s_w[NPOS];
  __shared__ alignas(16) float s_res[TILE_ELEMS];
  __shared__ int s_n;

  const int bid = blockIdx.x;
  const int r = bid >> 3;
  const int c0 = (bid & 7) * CTILE;
  const int tid = threadIdx.x;
  const int lc = tid & (CTILE - 1);
  const int g = tid >> 5;  // 0..7

  setup_roi<1>(rois, r, tid, s_off, s_w, &s_n);
  __syncthreads();

  const float* base = feats + (size_t)s_n * IMG_ELEMS + (size_t)(c0 + lc) * HW;
  float* s_row = s_res + lc * NPOS;
#pragma unroll 1
  for (int p = g; p < NPOS; p += 8) {
    const int4 o = s_off[p];
    const float4 w = s_w[p];
    s_row[p] = base[o.x] * w.x + base[o.y] * w.y + base[o.z] * w.z +
               base[o.w] * w.w;
  }
  __syncthreads();

  const float4* s4 = reinterpret_cast<const float4*>(s_res);
  float4* out4 = reinterpret_cast<float4*>(out + ((size_t)r * C + c0) * NPOS);
#pragma unroll 1
  for (int i = tid; i < TILE_ELEMS / 4; i += 256) {
    out4[i] = s4[i];
  }
}

extern "C" void kernel_launch(void* const* d_in, const int* in_sizes, int n_in,
                              void* d_out, int out_size, void* d_ws,
                              size_t ws_size, hipStream_t stream) {
  const float* feats = (const float*)d_in[0];
  const float* rois  = (const float*)d_in[1];
  float* out         = (float*)d_out;

  const size_t nhwc_bytes = (size_t)N_IMGS * HW * CU_ * sizeof(uint32_t);
  const size_t perm_off   = nhwc_bytes;                 // 4KB
  const size_t flags_off  = perm_off + R * sizeof(int); // 64B region
  const size_t need       = flags_off + 64;

  if (ws_size >= need) {
    uint32_t* nhwc = (uint32_t*)d_ws;
    int* perm = (int*)((char*)d_ws + perm_off);
    int* flg  = (int*)((char*)d_ws + flags_off);
    hipMemsetAsync(flg, 0, 64, stream);  // ticket + flags, every launch
    fused_roialign<<<dim3(GRID_PERSIST), dim3(512), 0, stream>>>(
        feats, rois, nhwc, perm, flg, out);
  } else {
    roi_align_nchw<<<dim3(R * NCT), dim3(256), 0, stream>>>(feats, rois, out);
  }
}

// Round 13
// 139.975 us; speedup vs baseline: 6.8918x; 6.8918x over previous
//
#include <hip/hip_runtime.h>
#include <stdint.h>

#define N_IMGS 8
#define C 256
#define H 128
#define W 128
#define R 1024
#define HOUT 14
#define WOUT 14
#define NPOS 196          // HOUT*WOUT
#define HW (H * W)        // 16384
#define IMG_ELEMS (C * HW)
#define CTILE 32          // channels per block (roi kernel)
#define NCT (C / CTILE)   // 8 channel tiles per roi
#define TILE_ELEMS (CTILE * NPOS)  // 6272 floats, contiguous in output
#define CU_ (C / 2)       // uints per NHWC row (bf16-pair packed) = 128

typedef float f4_t __attribute__((ext_vector_type(4)));
typedef float f2_t __attribute__((ext_vector_type(2)));

__device__ __forceinline__ unsigned short f2bf(float f) {  // RTNE
  uint32_t u = __float_as_uint(f);
  uint32_t r = u + 0x7FFFu + ((u >> 16) & 1u);
  return (unsigned short)(r >> 16);
}

// ---------------------------------------------------------------------------
// Kernel 1: NCHW -> NHWC transpose with bf16 pack + folded roi-by-image sort
// (one extra grid.x slot). Per transpose block: 64ch x 32hw; loads coalesced
// 128B/instr; stores pack 2 channels/uint, nontemporal (write-through -- the
// consumer is a separate dispatch on other XCDs; keep producer L2 clean).
// ~BW-bound (201MB round trip).
// ---------------------------------------------------------------------------
__global__ __launch_bounds__(256) void transpose_nchw_nhwc_bf16(
    const float* __restrict__ in, uint32_t* __restrict__ out,
    const float* __restrict__ rois, int* __restrict__ perm) {
  const int tx = threadIdx.x;  // 0..31
  const int ty = threadIdx.y;  // 0..7

  if (blockIdx.x == HW / 32) {
    // Sorter slot: one block does the counting sort, siblings exit.
    if (blockIdx.y != 0 || blockIdx.z != 0) return;
    __shared__ int hist[N_IMGS];
    __shared__ int cursor[N_IMGS];
    const int tid = ty * 32 + tx;
    if (tid < N_IMGS) hist[tid] = 0;
    __syncthreads();
    for (int i = tid; i < R; i += 256) {
      atomicAdd(&hist[(int)rois[i * 5]], 1);
    }
    __syncthreads();
    if (tid == 0) {
      int acc = 0;
      for (int k = 0; k < N_IMGS; ++k) {
        cursor[k] = acc;
        acc += hist[k];
      }
    }
    __syncthreads();
    for (int i = tid; i < R; i += 256) {
      const int b = (int)rois[i * 5];
      const int pos = atomicAdd(&cursor[b], 1);
      perm[pos] = i;  // output is permutation-invariant per roi
    }
    return;
  }

  __shared__ float tile[64][33];
  const int n   = blockIdx.z;
  const int hw0 = blockIdx.x * 32;
  const int c0  = blockIdx.y * 64;
  const float* inp = in + (size_t)n * IMG_ELEMS;
  uint32_t* outp   = out + (size_t)n * (size_t)HW * CU_;

#pragma unroll
  for (int i = 0; i < 8; ++i) {
    int cc = ty + i * 8;  // 0..63
    tile[cc][tx] = inp[(size_t)(c0 + cc) * HW + hw0 + tx];
  }
  __syncthreads();
#pragma unroll
  for (int i = 0; i < 4; ++i) {
    int hh = ty + i * 8;  // 0..31
    const uint32_t lo = f2bf(tile[2 * tx + 0][hh]);
    const uint32_t hi = f2bf(tile[2 * tx + 1][hh]);
    __builtin_nontemporal_store(
        lo | (hi << 16), &outp[(size_t)(hw0 + hh) * CU_ + (c0 >> 1) + tx]);
  }
}

// ---------------------------------------------------------------------------
// Geometry precompute: SoA offsets (pre-scaled by SCALE) and bilinear
// weights for all 196 positions of roi r into LDS.
// ---------------------------------------------------------------------------
template <int SCALE>
__device__ __forceinline__ void setup_roi_soa(const float* __restrict__ rois,
                                              int r, int tid, int* s_ox,
                                              int* s_oy, int* s_oz, int* s_ow,
                                              float4* s_w, int* s_n) {
  const float bf = rois[r * 5 + 0];
  const float x1 = rois[r * 5 + 1];
  const float y1 = rois[r * 5 + 2];
  const float x2 = rois[r * 5 + 3];
  const float y2 = rois[r * 5 + 4];
  if (tid == 0) *s_n = (int)bf;

  if (tid < NPOS) {
    const int ph = tid / WOUT;
    const int pw = tid - ph * WOUT;
    const float px_rel = (pw + 0.5f) / (float)WOUT;
    const float py_rel = (ph + 0.5f) / (float)HOUT;
    const float x_abs = px_rel * (x2 - x1) + x1;
    const float y_abs = py_rel * (y2 - y1) + y1;
    // rx = x_abs / W * 0.25 ; px = rx * W - 0.5  ==  x_abs * 0.25 - 0.5
    const float px = x_abs * 0.25f - 0.5f;
    const float py = y_abs * 0.25f - 0.5f;
    const float x0f = floorf(px);
    const float y0f = floorf(py);
    const float lx = px - x0f, ly = py - y0f;
    const float hx = 1.0f - lx, hy = 1.0f - ly;
    const int ix0 = (int)x0f;
    const int iy0 = (int)y0f;
    const int ix1 = ix0 + 1;
    const int iy1 = iy0 + 1;
    // Reference pads with zeros and clips into the pad -> OOB corners
    // contribute exactly 0. Reproduce by zeroing the weight.
    const bool vx0 = (ix0 >= 0) && (ix0 < W);
    const bool vx1 = (ix1 >= 0) && (ix1 < W);
    const bool vy0 = (iy0 >= 0) && (iy0 < H);
    const bool vy1 = (iy1 >= 0) && (iy1 < H);
    const int cx0 = min(max(ix0, 0), W - 1);
    const int cx1 = min(max(ix1, 0), W - 1);
    const int cy0 = min(max(iy0, 0), H - 1);
    const int cy1 = min(max(iy1, 0), H - 1);
    s_ox[tid] = (cy0 * W + cx0) * SCALE;
    s_oy[tid] = (cy1 * W + cx0) * SCALE;
    s_oz[tid] = (cy0 * W + cx1) * SCALE;
    s_ow[tid] = (cy1 * W + cx1) * SCALE;
    float4 w4;
    w4.x = (vx0 && vy0) ? hx * hy : 0.0f;
    w4.y = (vx0 && vy1) ? hx * ly : 0.0f;
    w4.z = (vx1 && vy0) ? lx * hy : 0.0f;
    w4.w = (vx1 && vy1) ? lx * ly : 0.0f;
    s_w[tid] = w4;
  }
}

// Unpack one bf16 pair (packed uint) to {lo, hi} floats.
__device__ __forceinline__ f2_t up2(uint32_t q) {
  f2_t v;
  v.x = __uint_as_float(q << 16);
  v.y = __uint_as_float(q & 0xFFFF0000u);
  return v;
}

// Bilinear combine for 8 channels (4 bf16 pairs) of one position; float2
// vector math -> packed f32 FMA. With wave-uniform lc8 and lane-consecutive
// p (= g), the LDS stores hit bank (const+g)%32: 2 lanes/bank, conflict-free
// (round-11's lc8-inner mapping was a 4-way conflict on every store).
__device__ __forceinline__ void acc8(float* s_base, int p, uint4 a, uint4 b,
                                     uint4 c, uint4 d, float4 w) {
  const uint32_t qa[4] = {a.x, a.y, a.z, a.w};
  const uint32_t qb[4] = {b.x, b.y, b.z, b.w};
  const uint32_t qc[4] = {c.x, c.y, c.z, c.w};
  const uint32_t qd[4] = {d.x, d.y, d.z, d.w};
#pragma unroll
  for (int j = 0; j < 4; ++j) {
    f2_t acc = up2(qa[j]) * w.x;
    acc += up2(qb[j]) * w.y;
    acc += up2(qc[j]) * w.z;
    acc += up2(qd[j]) * w.w;
    s_base[(2 * j + 0) * NPOS + p] = acc.x;
    s_base[(2 * j + 1) * NPOS + p] = acc.y;
  }
}

// ---------------------------------------------------------------------------
// Kernel 2: RoI Align, bf16 NHWC input, uint4 = 8-channel gathers.
// 512 threads/block: roi = perm[bid>>3] (image-grouped), c0 = (bid&7)*32.
// Thread: channel octet lc8 = tid>>7 (WAVE-UNIFORM), position g = tid&127;
// positions p0 = g, p1 = 128+g (g<68). Image-grouped roi order + ctile==bid%8
// keeps each XCD's gather set ~1MB -> L2-resident. Results staged in LDS in
// exact output layout (conflict-free stores, see acc8); nontemporal
// full-line writeout.
// ---------------------------------------------------------------------------
__global__ __launch_bounds__(512, 6) void roi_align_nhwc_bf16(
    const uint32_t* __restrict__ feats, const float* __restrict__ rois,
    const int* __restrict__ perm, float* __restrict__ out) {
  __shared__ int s_ox[NPOS], s_oy[NPOS], s_oz[NPOS], s_ow[NPOS];
  __shared__ float4 s_w[NPOS];
  __shared__ alignas(16) float s_res[TILE_ELEMS];  // [CTILE][NPOS] = out slice
  __shared__ int s_n;

  const int bid = blockIdx.x;
  const int r   = perm[bid >> 3];
  const int c0  = (bid & 7) * CTILE;
  const int tid = threadIdx.x;
  const int lc8 = tid >> 7;   // channel octet within tile, wave-uniform
  const int g   = tid & 127;  // position group, lane-consecutive

  setup_roi_soa<CU_>(rois, r, tid, s_ox, s_oy, s_oz, s_ow, s_w, &s_n);
  __syncthreads();

  const uint32_t* base =
      feats + (size_t)s_n * (size_t)HW * CU_ + (c0 >> 1) + lc8 * 4;
  float* s_base = s_res + (lc8 * 8) * NPOS;

  const bool has1 = g < (NPOS - 128);  // g < 68
  const int p1 = 128 + g;

  // Issue all gathers (up to 8 uint4) before any consumption.
  const float4 w0 = s_w[g];
  uint4 A0 = *reinterpret_cast<const uint4*>(base + s_ox[g]);
  uint4 B0 = *reinterpret_cast<const uint4*>(base + s_oy[g]);
  uint4 C0 = *reinterpret_cast<const uint4*>(base + s_oz[g]);
  uint4 D0 = *reinterpret_cast<const uint4*>(base + s_ow[g]);
  if (has1) {
    const float4 w1 = s_w[p1];
    const uint4 A1 = *reinterpret_cast<const uint4*>(base + s_ox[p1]);
    const uint4 B1 = *reinterpret_cast<const uint4*>(base + s_oy[p1]);
    const uint4 C1 = *reinterpret_cast<const uint4*>(base + s_oz[p1]);
    const uint4 D1 = *reinterpret_cast<const uint4*>(base + s_ow[p1]);
    acc8(s_base, g, A0, B0, C0, D0, w0);
    acc8(s_base, p1, A1, B1, C1, D1, w1);
  } else {
    acc8(s_base, g, A0, B0, C0, D0, w0);
  }
  __syncthreads();

  // Stream the tile out: contiguous 25088B, nontemporal 16B stores.
  const f4_t* s4 = reinterpret_cast<const f4_t*>(s_res);
  f4_t* out4 = reinterpret_cast<f4_t*>(out + ((size_t)r * C + c0) * NPOS);
#pragma unroll 1
  for (int i = tid; i < TILE_ELEMS / 4; i += 512) {
    __builtin_nontemporal_store(s4[i], &out4[i]);
  }
}

// ---------------------------------------------------------------------------
// Fallback (ws too small): scalar gathers straight from NCHW. Correct, slow.
// ---------------------------------------------------------------------------
__global__ __launch_bounds__(256, 4) void roi_align_nchw(
    const float* __restrict__ feats, const float* __restrict__ rois,
    float* __restrict__ out) {
  __shared__ int s_ox[NPOS], s_oy[NPOS], s_oz[NPOS], s_ow[NPOS];
  __shared__ float4 s_w[NPOS];
  __shared__ alignas(16) float s_res[TILE_ELEMS];
  __shared__ int s_n;

  const int bid = blockIdx.x;
  const int r = bid >> 3;
  const int c0 = (bid & 7) * CTILE;
  const int tid = threadIdx.x;
  const int lc = tid & (CTILE - 1);
  const int g = tid >> 5;  // 0..7

  setup_roi_soa<1>(rois, r, tid, s_ox, s_oy, s_oz, s_ow, s_w, &s_n);
  __syncthreads();

  const float* base = feats + (size_t)s_n * IMG_ELEMS + (size_t)(c0 + lc) * HW;
  float* s_row = s_res + lc * NPOS;
#pragma unroll 1
  for (int p = g; p < NPOS; p += 8) {
    const float4 w = s_w[p];
    s_row[p] = base[s_ox[p]] * w.x + base[s_oy[p]] * w.y +
               base[s_oz[p]] * w.z + base[s_ow[p]] * w.w;
  }
  __syncthreads();

  const float4* s4 = reinterpret_cast<const float4*>(s_res);
  float4* out4 = reinterpret_cast<float4*>(out + ((size_t)r * C + c0) * NPOS);
#pragma unroll 1
  for (int i = tid; i < TILE_ELEMS / 4; i += 256) {
    out4[i] = s4[i];
  }
}

extern "C" void kernel_launch(void* const* d_in, const int* in_sizes, int n_in,
                              void* d_out, int out_size, void* d_ws,
                              size_t ws_size, hipStream_t stream) {
  const float* feats = (const float*)d_in[0];
  const float* rois  = (const float*)d_in[1];
  float* out         = (float*)d_out;

  const size_t nhwc_bytes = (size_t)N_IMGS * HW * CU_ * sizeof(uint32_t);
  const size_t need = nhwc_bytes + (size_t)R * sizeof(int);
  if (ws_size >= need) {
    uint32_t* nhwc16 = (uint32_t*)d_ws;
    int* perm = (int*)((char*)d_ws + nhwc_bytes);
    dim3 tb(32, 8);
    dim3 tg(HW / 32 + 1, C / 64, N_IMGS);  // +1 slot hosts the roi sort
    transpose_nchw_nhwc_bf16<<<tg, tb, 0, stream>>>(feats, nhwc16, rois, perm);
    roi_align_nhwc_bf16<<<dim3(R * NCT), dim3(512), 0, stream>>>(nhwc16, rois,
                                                                 perm, out);
  } else {
    roi_align_nchw<<<dim3(R * NCT), dim3(256), 0, stream>>>(feats, rois, out);
  }
}

// Round 14
// 109.063 us; speedup vs baseline: 8.8451x; 1.2834x over previous
//
#include <hip/hip_runtime.h>
#include <stdint.h>

#define N_IMGS 8
#define C 256
#define H 128
#define W 128
#define R 1024
#define HOUT 14
#define WOUT 14
#define NPOS 196          // HOUT*WOUT
#define HW (H * W)        // 16384
#define IMG_ELEMS (C * HW)
#define CTILE 32          // channels per block (roi kernel)
#define NCT (C / CTILE)   // 8 channel tiles per roi
#define TILE_ELEMS (CTILE * NPOS)  // 6272 floats, contiguous in output
#define CU_ (C / 2)       // uints per NHWC row (bf16-pair packed) = 128

typedef float f4_t __attribute__((ext_vector_type(4)));
typedef float f2_t __attribute__((ext_vector_type(2)));

__device__ __forceinline__ unsigned short f2bf(float f) {  // RTNE
  uint32_t u = __float_as_uint(f);
  uint32_t r = u + 0x7FFFu + ((u >> 16) & 1u);
  return (unsigned short)(r >> 16);
}

// ---------------------------------------------------------------------------
// Kernel 1: NCHW -> NHWC transpose with bf16 pack + folded roi-by-image sort
// (one extra grid.x slot). Per transpose block: 64ch x 32hw; loads coalesced
// 128B/instr; stores pack 2 channels/uint, nontemporal. ~BW-bound.
// ---------------------------------------------------------------------------
__global__ __launch_bounds__(256) void transpose_nchw_nhwc_bf16(
    const float* __restrict__ in, uint32_t* __restrict__ out,
    const float* __restrict__ rois, int* __restrict__ perm) {
  const int tx = threadIdx.x;  // 0..31
  const int ty = threadIdx.y;  // 0..7

  if (blockIdx.x == HW / 32) {
    // Sorter slot: one block does the counting sort, siblings exit.
    if (blockIdx.y != 0 || blockIdx.z != 0) return;
    __shared__ int hist[N_IMGS];
    __shared__ int cursor[N_IMGS];
    const int tid = ty * 32 + tx;
    if (tid < N_IMGS) hist[tid] = 0;
    __syncthreads();
    for (int i = tid; i < R; i += 256) {
      atomicAdd(&hist[(int)rois[i * 5]], 1);
    }
    __syncthreads();
    if (tid == 0) {
      int acc = 0;
      for (int k = 0; k < N_IMGS; ++k) {
        cursor[k] = acc;
        acc += hist[k];
      }
    }
    __syncthreads();
    for (int i = tid; i < R; i += 256) {
      const int b = (int)rois[i * 5];
      const int pos = atomicAdd(&cursor[b], 1);
      perm[pos] = i;  // output is permutation-invariant per roi
    }
    return;
  }

  __shared__ float tile[64][33];
  const int n   = blockIdx.z;
  const int hw0 = blockIdx.x * 32;
  const int c0  = blockIdx.y * 64;
  const float* inp = in + (size_t)n * IMG_ELEMS;
  uint32_t* outp   = out + (size_t)n * (size_t)HW * CU_;

#pragma unroll
  for (int i = 0; i < 8; ++i) {
    int cc = ty + i * 8;  // 0..63
    tile[cc][tx] = inp[(size_t)(c0 + cc) * HW + hw0 + tx];
  }
  __syncthreads();
#pragma unroll
  for (int i = 0; i < 4; ++i) {
    int hh = ty + i * 8;  // 0..31
    const uint32_t lo = f2bf(tile[2 * tx + 0][hh]);
    const uint32_t hi = f2bf(tile[2 * tx + 1][hh]);
    __builtin_nontemporal_store(
        lo | (hi << 16), &outp[(size_t)(hw0 + hh) * CU_ + (c0 >> 1) + tx]);
  }
}

// ---------------------------------------------------------------------------
// Geometry precompute: offsets (pre-scaled by SCALE) and bilinear weights
// for all 196 positions of roi r into LDS (AoS int4: 4 lanes sharing one
// position broadcast-read a single b128 -- conflict-free).
// ---------------------------------------------------------------------------
template <int SCALE>
__device__ __forceinline__ void setup_roi(const float* __restrict__ rois,
                                          int r, int tid, int4* s_off,
                                          float4* s_w, int* s_n) {
  const float bf = rois[r * 5 + 0];
  const float x1 = rois[r * 5 + 1];
  const float y1 = rois[r * 5 + 2];
  const float x2 = rois[r * 5 + 3];
  const float y2 = rois[r * 5 + 4];
  if (tid == 0) *s_n = (int)bf;

  if (tid < NPOS) {
    const int ph = tid / WOUT;
    const int pw = tid - ph * WOUT;
    const float px_rel = (pw + 0.5f) / (float)WOUT;
    const float py_rel = (ph + 0.5f) / (float)HOUT;
    const float x_abs = px_rel * (x2 - x1) + x1;
    const float y_abs = py_rel * (y2 - y1) + y1;
    // rx = x_abs / W * 0.25 ; px = rx * W - 0.5  ==  x_abs * 0.25 - 0.5
    const float px = x_abs * 0.25f - 0.5f;
    const float py = y_abs * 0.25f - 0.5f;
    const float x0f = floorf(px);
    const float y0f = floorf(py);
    const float lx = px - x0f, ly = py - y0f;
    const float hx = 1.0f - lx, hy = 1.0f - ly;
    const int ix0 = (int)x0f;
    const int iy0 = (int)y0f;
    const int ix1 = ix0 + 1;
    const int iy1 = iy0 + 1;
    // Reference pads with zeros and clips into the pad -> OOB corners
    // contribute exactly 0. Reproduce by zeroing the weight.
    const bool vx0 = (ix0 >= 0) && (ix0 < W);
    const bool vx1 = (ix1 >= 0) && (ix1 < W);
    const bool vy0 = (iy0 >= 0) && (iy0 < H);
    const bool vy1 = (iy1 >= 0) && (iy1 < H);
    const int cx0 = min(max(ix0, 0), W - 1);
    const int cx1 = min(max(ix1, 0), W - 1);
    const int cy0 = min(max(iy0, 0), H - 1);
    const int cy1 = min(max(iy1, 0), H - 1);
    int4 o;
    o.x = (cy0 * W + cx0) * SCALE;
    o.y = (cy1 * W + cx0) * SCALE;
    o.z = (cy0 * W + cx1) * SCALE;
    o.w = (cy1 * W + cx1) * SCALE;
    float4 w4;
    w4.x = (vx0 && vy0) ? hx * hy : 0.0f;
    w4.y = (vx0 && vy1) ? hx * ly : 0.0f;
    w4.z = (vx1 && vy0) ? lx * hy : 0.0f;
    w4.w = (vx1 && vy1) ? lx * ly : 0.0f;
    s_off[tid] = o;
    s_w[tid]   = w4;
  }
}

// Unpack one bf16 pair (packed uint) to {lo, hi} floats.
__device__ __forceinline__ f2_t up2(uint32_t q) {
  f2_t v;
  v.x = __uint_as_float(q << 16);
  v.y = __uint_as_float(q & 0xFFFF0000u);
  return v;
}

// Bilinear combine for 8 channels (4 bf16 pairs) of one position; float2
// vector math -> packed f32 FMA. NOTE: with lc8=tid&3 the LDS stores are a
// 4-way bank conflict (lc8*8*196 % 32 == 0). Measured cost <= ~5us; every
// alternative (row rotation, padding, position-major) either breaks the
// 64B-coalesced gathers (round 13: +70us!), the 16B-aligned writeout, or
// needs runtime-indexed register arrays (scratch). Accepted.
__device__ __forceinline__ void acc8(float* s_base, int p, uint4 a, uint4 b,
                                     uint4 c, uint4 d, float4 w) {
  const uint32_t qa[4] = {a.x, a.y, a.z, a.w};
  const uint32_t qb[4] = {b.x, b.y, b.z, b.w};
  const uint32_t qc[4] = {c.x, c.y, c.z, c.w};
  const uint32_t qd[4] = {d.x, d.y, d.z, d.w};
#pragma unroll
  for (int j = 0; j < 4; ++j) {
    f2_t acc = up2(qa[j]) * w.x;
    acc += up2(qb[j]) * w.y;
    acc += up2(qc[j]) * w.z;
    acc += up2(qd[j]) * w.w;
    s_base[(2 * j + 0) * NPOS + p] = acc.x;
    s_base[(2 * j + 1) * NPOS + p] = acc.y;
  }
}

// ---------------------------------------------------------------------------
// Kernel 2: RoI Align, bf16 NHWC input, uint4 = 8-channel gathers.
// 512 threads/block: roi = perm[bid>>3] (image-grouped), c0 = (bid&7)*32.
// Thread: channel octet lc8 = tid&3, position group g = tid>>2 (0..127);
// positions p0 = g, p1 = 128+g (g<68). Groups of 4 lanes read one position's
// 4 consecutive uint4 = 64B full lines (COALESCING-CRITICAL: do not remap --
// round 13's wave-uniform lc8 quadrupled L2 requests, +70us). Image-grouped
// roi order + ctile==bid%8 keeps each XCD's gather set ~1MB -> L2-resident.
// Results staged in LDS in exact output layout; nontemporal full-line
// writeout.
// ---------------------------------------------------------------------------
__global__ __launch_bounds__(512, 6) void roi_align_nhwc_bf16(
    const uint32_t* __restrict__ feats, const float* __restrict__ rois,
    const int* __restrict__ perm, float* __restrict__ out) {
  __shared__ int4   s_off[NPOS];   // uint-offsets, pre-scaled by CU_
  __shared__ float4 s_w[NPOS];
  __shared__ alignas(16) float s_res[TILE_ELEMS];  // [CTILE][NPOS] = out slice
  __shared__ int s_n;

  const int bid = blockIdx.x;
  const int r   = perm[bid >> 3];
  const int c0  = (bid & 7) * CTILE;
  const int tid = threadIdx.x;
  const int lc8 = tid & 3;   // channel octet within tile
  const int g   = tid >> 2;  // 0..127 position group

  setup_roi<CU_>(rois, r, tid, s_off, s_w, &s_n);
  __syncthreads();

  const uint32_t* base =
      feats + (size_t)s_n * (size_t)HW * CU_ + (c0 >> 1) + lc8 * 4;
  float* s_base = s_res + (lc8 * 8) * NPOS;

  const bool has1 = g < (NPOS - 128);  // g < 68
  const int p1 = 128 + g;

  // Issue all gathers (up to 8 uint4) before any consumption.
  const int4   o0 = s_off[g];
  const float4 w0 = s_w[g];
  uint4 A0 = *reinterpret_cast<const uint4*>(base + o0.x);
  uint4 B0 = *reinterpret_cast<const uint4*>(base + o0.y);
  uint4 C0 = *reinterpret_cast<const uint4*>(base + o0.z);
  uint4 D0 = *reinterpret_cast<const uint4*>(base + o0.w);
  if (has1) {
    const int4   o1 = s_off[p1];
    const float4 w1 = s_w[p1];
    const uint4 A1 = *reinterpret_cast<const uint4*>(base + o1.x);
    const uint4 B1 = *reinterpret_cast<const uint4*>(base + o1.y);
    const uint4 C1 = *reinterpret_cast<const uint4*>(base + o1.z);
    const uint4 D1 = *reinterpret_cast<const uint4*>(base + o1.w);
    acc8(s_base, g, A0, B0, C0, D0, w0);
    acc8(s_base, p1, A1, B1, C1, D1, w1);
  } else {
    acc8(s_base, g, A0, B0, C0, D0, w0);
  }
  __syncthreads();

  // Stream the tile out: contiguous 25088B, nontemporal 16B stores.
  const f4_t* s4 = reinterpret_cast<const f4_t*>(s_res);
  f4_t* out4 = reinterpret_cast<f4_t*>(out + ((size_t)r * C + c0) * NPOS);
#pragma unroll 1
  for (int i = tid; i < TILE_ELEMS / 4; i += 512) {
    __builtin_nontemporal_store(s4[i], &out4[i]);
  }
}

// ---------------------------------------------------------------------------
// Fallback (ws too small): scalar gathers straight from NCHW. Correct, slow.
// ---------------------------------------------------------------------------
__global__ __launch_bounds__(256, 4) void roi_align_nchw(
    const float* __restrict__ feats, const float* __restrict__ rois,
    float* __restrict__ out) {
  __shared__ int4   s_off[NPOS];
  __shared__ float4 s_w[NPOS];
  __shared__ alignas(16) float s_res[TILE_ELEMS];
  __shared__ int s_n;

  const int bid = blockIdx.x;
  const int r = bid >> 3;
  const int c0 = (bid & 7) * CTILE;
  const int tid = threadIdx.x;
  const int lc = tid & (CTILE - 1);
  const int g = tid >> 5;  // 0..7

  setup_roi<1>(rois, r, tid, s_off, s_w, &s_n);
  __syncthreads();

  const float* base = feats + (size_t)s_n * IMG_ELEMS + (size_t)(c0 + lc) * HW;
  float* s_row = s_res + lc * NPOS;
#pragma unroll 1
  for (int p = g; p < NPOS; p += 8) {
    const int4 o = s_off[p];
    const float4 w = s_w[p];
    s_row[p] = base[o.x] * w.x + base[o.y] * w.y + base[o.z] * w.z +
               base[o.w] * w.w;
  }
  __syncthreads();

  const float4* s4 = reinterpret_cast<const float4*>(s_res);
  float4* out4 = reinterpret_cast<float4*>(out + ((size_t)r * C + c0) * NPOS);
#pragma unroll 1
  for (int i = tid; i < TILE_ELEMS / 4; i += 256) {
    out4[i] = s4[i];
  }
}

extern "C" void kernel_launch(void* const* d_in, const int* in_sizes, int n_in,
                              void* d_out, int out_size, void* d_ws,
                              size_t ws_size, hipStream_t stream) {
  const float* feats = (const float*)d_in[0];
  const float* rois  = (const float*)d_in[1];
  float* out         = (float*)d_out;

  const size_t nhwc_bytes = (size_t)N_IMGS * HW * CU_ * sizeof(uint32_t);
  const size_t need = nhwc_bytes + (size_t)R * sizeof(int);
  if (ws_size >= need) {
    uint32_t* nhwc16 = (uint32_t*)d_ws;
    int* perm = (int*)((char*)d_ws + nhwc_bytes);
    dim3 tb(32, 8);
    dim3 tg(HW / 32 + 1, C / 64, N_IMGS);  // +1 slot hosts the roi sort
    transpose_nchw_nhwc_bf16<<<tg, tb, 0, stream>>>(feats, nhwc16, rois, perm);
    roi_align_nhwc_bf16<<<dim3(R * NCT), dim3(512), 0, stream>>>(nhwc16, rois,
                                                                 perm, out);
  } else {
    roi_align_nchw<<<dim3(R * NCT), dim3(256), 0, stream>>>(feats, rois, out);
  }
}

// Round 15
// 81.010 us; speedup vs baseline: 11.9082x; 1.3463x over previous
//
#include <hip/hip_runtime.h>
#include <stdint.h>

#define N_IMGS 8
#define C 256
#define H 128
#define W 128
#define R 1024
#define HOUT 14
#define WOUT 14
#define NPOS 196          // HOUT*WOUT
#define HW (H * W)        // 16384
#define IMG_ELEMS (C * HW)
#define CTILE 32          // channels per block (roi kernel)
#define NCT (C / CTILE)   // 8 channel tiles per roi
#define TILE_ELEMS (CTILE * NPOS)  // 6272 floats, contiguous in output
#define CU_ (C / 2)       // uints per NHWC row (bf16-pair packed) = 128

typedef float f4_t __attribute__((ext_vector_type(4)));  // native vec for NT store
typedef float f2_t __attribute__((ext_vector_type(2)));  // for v_pk_fma_f32

__device__ __forceinline__ unsigned short f2bf(float f) {  // RTNE
  uint32_t u = __float_as_uint(f);
  uint32_t r = u + 0x7FFFu + ((u >> 16) & 1u);
  return (unsigned short)(r >> 16);
}

// ---------------------------------------------------------------------------
// Kernel 1: NCHW -> NHWC transpose with bf16 pack, with the roi-by-image
// counting sort folded into one extra grid.x slot. Per transpose block:
// 64ch x 32hw; loads coalesced 128B/instr; stores pack 2 channels/uint ->
// 128B/instr. REGULAR (write-back) stores on purpose: the roi kernel
// consumes this buffer, and cache residency is part of the gather-locality
// win. Round 13/14 used nontemporal here and lost ~28us (consumer re-fetched
// ~67MB from HBM). NT is only for the final output.
// ---------------------------------------------------------------------------
__global__ __launch_bounds__(256) void transpose_nchw_nhwc_bf16(
    const float* __restrict__ in, uint32_t* __restrict__ out,
    const float* __restrict__ rois, int* __restrict__ perm) {
  const int tx = threadIdx.x;  // 0..31
  const int ty = threadIdx.y;  // 0..7

  if (blockIdx.x == HW / 32) {
    // Sorter slot: one block does the counting sort, siblings exit.
    if (blockIdx.y != 0 || blockIdx.z != 0) return;
    __shared__ int hist[N_IMGS];
    __shared__ int cursor[N_IMGS];
    const int tid = ty * 32 + tx;
    if (tid < N_IMGS) hist[tid] = 0;
    __syncthreads();
    for (int i = tid; i < R; i += 256) {
      atomicAdd(&hist[(int)rois[i * 5]], 1);
    }
    __syncthreads();
    if (tid == 0) {
      int acc = 0;
      for (int k = 0; k < N_IMGS; ++k) {
        cursor[k] = acc;
        acc += hist[k];
      }
    }
    __syncthreads();
    for (int i = tid; i < R; i += 256) {
      const int b = (int)rois[i * 5];
      const int pos = atomicAdd(&cursor[b], 1);
      perm[pos] = i;  // output is permutation-invariant per roi
    }
    return;
  }

  __shared__ float tile[64][33];
  const int n   = blockIdx.z;
  const int hw0 = blockIdx.x * 32;
  const int c0  = blockIdx.y * 64;
  const float* inp = in + (size_t)n * IMG_ELEMS;
  uint32_t* outp   = out + (size_t)n * (size_t)HW * CU_;

#pragma unroll
  for (int i = 0; i < 8; ++i) {
    int cc = ty + i * 8;  // 0..63
    tile[cc][tx] = inp[(size_t)(c0 + cc) * HW + hw0 + tx];
  }
  __syncthreads();
#pragma unroll
  for (int i = 0; i < 4; ++i) {
    int hh = ty + i * 8;  // 0..31
    const uint32_t lo = f2bf(tile[2 * tx + 0][hh]);
    const uint32_t hi = f2bf(tile[2 * tx + 1][hh]);
    outp[(size_t)(hw0 + hh) * CU_ + (c0 >> 1) + tx] = lo | (hi << 16);
  }
}

// ---------------------------------------------------------------------------
// Geometry precompute: offsets (pre-scaled by SCALE) and bilinear weights
// for all 196 positions of roi r into LDS.
// ---------------------------------------------------------------------------
template <int SCALE>
__device__ __forceinline__ void setup_roi(const float* __restrict__ rois,
                                          int r, int tid, int4* s_off,
                                          float4* s_w, int* s_n) {
  const float bf = rois[r * 5 + 0];
  const float x1 = rois[r * 5 + 1];
  const float y1 = rois[r * 5 + 2];
  const float x2 = rois[r * 5 + 3];
  const float y2 = rois[r * 5 + 4];
  if (tid == 0) *s_n = (int)bf;

  if (tid < NPOS) {
    const int ph = tid / WOUT;
    const int pw = tid - ph * WOUT;
    const float px_rel = (pw + 0.5f) / (float)WOUT;
    const float py_rel = (ph + 0.5f) / (float)HOUT;
    const float x_abs = px_rel * (x2 - x1) + x1;
    const float y_abs = py_rel * (y2 - y1) + y1;
    // rx = x_abs / W * 0.25 ; px = rx * W - 0.5  ==  x_abs * 0.25 - 0.5
    const float px = x_abs * 0.25f - 0.5f;
    const float py = y_abs * 0.25f - 0.5f;
    const float x0f = floorf(px);
    const float y0f = floorf(py);
    const float lx = px - x0f, ly = py - y0f;
    const float hx = 1.0f - lx, hy = 1.0f - ly;
    const int ix0 = (int)x0f;
    const int iy0 = (int)y0f;
    const int ix1 = ix0 + 1;
    const int iy1 = iy0 + 1;
    // Reference pads with zeros and clips into the pad -> OOB corners
    // contribute exactly 0. Reproduce by zeroing the weight.
    const bool vx0 = (ix0 >= 0) && (ix0 < W);
    const bool vx1 = (ix1 >= 0) && (ix1 < W);
    const bool vy0 = (iy0 >= 0) && (iy0 < H);
    const bool vy1 = (iy1 >= 0) && (iy1 < H);
    const int cx0 = min(max(ix0, 0), W - 1);
    const int cx1 = min(max(ix1, 0), W - 1);
    const int cy0 = min(max(iy0, 0), H - 1);
    const int cy1 = min(max(iy1, 0), H - 1);
    int4 o;
    o.x = (cy0 * W + cx0) * SCALE;
    o.y = (cy1 * W + cx0) * SCALE;
    o.z = (cy0 * W + cx1) * SCALE;
    o.w = (cy1 * W + cx1) * SCALE;
    float4 w4;
    w4.x = (vx0 && vy0) ? hx * hy : 0.0f;
    w4.y = (vx0 && vy1) ? hx * ly : 0.0f;
    w4.z = (vx1 && vy0) ? lx * hy : 0.0f;
    w4.w = (vx1 && vy1) ? lx * ly : 0.0f;
    s_off[tid] = o;
    s_w[tid]   = w4;
  }
}

// Unpack one bf16 pair (packed uint) to {lo, hi} floats.
__device__ __forceinline__ f2_t up2(uint32_t q) {
  f2_t v;
  v.x = __uint_as_float(q << 16);
  v.y = __uint_as_float(q & 0xFFFF0000u);
  return v;
}

// Bilinear combine for 8 channels (4 bf16 pairs) of one position; float2
// vector math -> packed f32 FMA. NOTE: with lc8=tid&3 the LDS stores are a
// 4-way bank conflict; measured cost <= ~5us and every alternative broke
// something bigger (round 13: wave-uniform lc8 destroyed gather coalescing,
// +70us). Accepted.
__device__ __forceinline__ void acc8(float* s_base, int p, uint4 a, uint4 b,
                                     uint4 c, uint4 d, float4 w) {
  const uint32_t qa[4] = {a.x, a.y, a.z, a.w};
  const uint32_t qb[4] = {b.x, b.y, b.z, b.w};
  const uint32_t qc[4] = {c.x, c.y, c.z, c.w};
  const uint32_t qd[4] = {d.x, d.y, d.z, d.w};
#pragma unroll
  for (int j = 0; j < 4; ++j) {
    f2_t acc = up2(qa[j]) * w.x;
    acc += up2(qb[j]) * w.y;
    acc += up2(qc[j]) * w.z;
    acc += up2(qd[j]) * w.w;
    s_base[(2 * j + 0) * NPOS + p] = acc.x;
    s_base[(2 * j + 1) * NPOS + p] = acc.y;
  }
}

// ---------------------------------------------------------------------------
// Kernel 2: RoI Align, bf16 NHWC input, uint4 = 8-channel gathers.
// 512 threads/block: roi = perm[bid>>3] (image-grouped), c0 = (bid&7)*32.
// Thread: channel octet lc8 = tid&3, position group g = tid>>2 in 0..127;
// positions p0 = g, p1 = 128+g (g<68). Groups of 4 lanes read one position's
// 4 consecutive uint4 = 64B full lines (coalescing-critical, round-13
// lesson). Image-grouped roi order + ctile==bid%8 keeps each XCD's gather
// set ~1MB -> L2-resident. Results staged in LDS in exact output layout;
// nontemporal full-line writeout (final output only).
// ---------------------------------------------------------------------------
__global__ __launch_bounds__(512, 6) void roi_align_nhwc_bf16(
    const uint32_t* __restrict__ feats, const float* __restrict__ rois,
    const int* __restrict__ perm, float* __restrict__ out) {
  __shared__ int4   s_off[NPOS];   // uint-offsets, pre-scaled by CU_
  __shared__ float4 s_w[NPOS];
  __shared__ alignas(16) float s_res[TILE_ELEMS];  // [CTILE][NPOS] = out slice
  __shared__ int s_n;

  const int bid = blockIdx.x;
  const int r   = perm[bid >> 3];
  const int c0  = (bid & 7) * CTILE;
  const int tid = threadIdx.x;
  const int lc8 = tid & 3;   // channel octet within tile
  const int g   = tid >> 2;  // 0..127 position group

  setup_roi<CU_>(rois, r, tid, s_off, s_w, &s_n);
  __syncthreads();

  const uint32_t* base =
      feats + (size_t)s_n * (size_t)HW * CU_ + (c0 >> 1) + lc8 * 4;
  float* s_base = s_res + (lc8 * 8) * NPOS;

  const bool has1 = g < (NPOS - 128);  // g < 68
  const int p1 = 128 + g;

  // Issue all gathers (up to 8 uint4) before any consumption.
  const int4   o0 = s_off[g];
  const float4 w0 = s_w[g];
  uint4 A0 = *reinterpret_cast<const uint4*>(base + o0.x);
  uint4 B0 = *reinterpret_cast<const uint4*>(base + o0.y);
  uint4 C0 = *reinterpret_cast<const uint4*>(base + o0.z);
  uint4 D0 = *reinterpret_cast<const uint4*>(base + o0.w);
  if (has1) {
    const int4   o1 = s_off[p1];
    const float4 w1 = s_w[p1];
    const uint4 A1 = *reinterpret_cast<const uint4*>(base + o1.x);
    const uint4 B1 = *reinterpret_cast<const uint4*>(base + o1.y);
    const uint4 C1 = *reinterpret_cast<const uint4*>(base + o1.z);
    const uint4 D1 = *reinterpret_cast<const uint4*>(base + o1.w);
    acc8(s_base, g, A0, B0, C0, D0, w0);
    acc8(s_base, p1, A1, B1, C1, D1, w1);
  } else {
    acc8(s_base, g, A0, B0, C0, D0, w0);
  }
  __syncthreads();

  // Stream the tile out: contiguous 25088B, nontemporal 16B stores.
  const f4_t* s4 = reinterpret_cast<const f4_t*>(s_res);
  f4_t* out4 = reinterpret_cast<f4_t*>(out + ((size_t)r * C + c0) * NPOS);
#pragma unroll 1
  for (int i = tid; i < TILE_ELEMS / 4; i += 512) {
    __builtin_nontemporal_store(s4[i], &out4[i]);
  }
}

// ---------------------------------------------------------------------------
// Fallback (ws too small): scalar gathers straight from NCHW. Correct, slow.
// ---------------------------------------------------------------------------
__global__ __launch_bounds__(256, 4) void roi_align_nchw(
    const float* __restrict__ feats, const float* __restrict__ rois,
    float* __restrict__ out) {
  __shared__ int4   s_off[NPOS];
  __shared__ float4 s_w[NPOS];
  __shared__ alignas(16) float s_res[TILE_ELEMS];
  __shared__ int s_n;

  const int bid = blockIdx.x;
  const int r = bid >> 3;
  const int c0 = (bid & 7) * CTILE;
  const int tid = threadIdx.x;
  const int lc = tid & (CTILE - 1);
  const int g = tid >> 5;  // 0..7

  setup_roi<1>(rois, r, tid, s_off, s_w, &s_n);
  __syncthreads();

  const float* base = feats + (size_t)s_n * IMG_ELEMS + (size_t)(c0 + lc) * HW;
  float* s_row = s_res + lc * NPOS;
#pragma unroll 1
  for (int p = g; p < NPOS; p += 8) {
    const int4 o = s_off[p];
    const float4 w = s_w[p];
    s_row[p] = base[o.x] * w.x + base[o.y] * w.y + base[o.z] * w.z +
               base[o.w] * w.w;
  }
  __syncthreads();

  const float4* s4 = reinterpret_cast<const float4*>(s_res);
  float4* out4 = reinterpret_cast<float4*>(out + ((size_t)r * C + c0) * NPOS);
#pragma unroll 1
  for (int i = tid; i < TILE_ELEMS / 4; i += 256) {
    out4[i] = s4[i];
  }
}

extern "C" void kernel_launch(void* const* d_in, const int* in_sizes, int n_in,
                              void* d_out, int out_size, void* d_ws,
                              size_t ws_size, hipStream_t stream) {
  const float* feats = (const float*)d_in[0];
  const float* rois  = (const float*)d_in[1];
  float* out         = (float*)d_out;

  const size_t nhwc_bytes = (size_t)N_IMGS * HW * CU_ * sizeof(uint32_t);
  const size_t need = nhwc_bytes + (size_t)R * sizeof(int);
  if (ws_size >= need) {
    uint32_t* nhwc16 = (uint32_t*)d_ws;
    int* perm = (int*)((char*)d_ws + nhwc_bytes);
    dim3 tb(32, 8);
    dim3 tg(HW / 32 + 1, C / 64, N_IMGS);  // +1 slot hosts the roi sort
    transpose_nchw_nhwc_bf16<<<tg, tb, 0, stream>>>(feats, nhwc16, rois, perm);
    roi_align_nhwc_bf16<<<dim3(R * NCT), dim3(512), 0, stream>>>(nhwc16, rois,
                                                                 perm, out);
  } else {
    roi_align_nchw<<<dim3(R * NCT), dim3(256), 0, stream>>>(feats, rois, out);
  }
}